// Round 6
// baseline (65.296 us; speedup 1.0000x reference)
//
#include <hip/hip_runtime.h>

// RefinementCAM: B=4, C=256, H=W=64, N=4096.
// out[b,n] = s[b,n] * (feat[b,:,n] . v[b,:]),
//   v[b,c] = sum_m feat[b,c,m] * w[b,m],  w = s*cam,
//   s = m/max(m*||feat[:,n]||,1e-12),  m in {0,1/3,2/3,1}.
// 2 kernels. K1: cold feat pass -> norm + v-partials (LDS-stashed tile).
// K2: v-reduce (16 blocks) + out + minmax + rescale + loss, with all
// cross-block communication via AGENT-scope atomics (NO threadfence).

constexpr int B    = 4;
constexpr int C    = 256;
constexpr int N    = 4096;
constexpr int BN   = B * N;       // 16384
constexpr int CN   = C * N;
constexpr int NBLK = 512;         // 32 pixels per block
constexpr int NRED = 16;          // v-reducer blocks in K2

#define SCOPE_AGENT __HIP_MEMORY_SCOPE_AGENT

__device__ __forceinline__ float wsum(float v) {
#pragma unroll
    for (int o = 32; o > 0; o >>= 1) v += __shfl_down(v, o, 64);
    return v;
}
__device__ __forceinline__ float wmin64(float v) {
#pragma unroll
    for (int o = 32; o > 0; o >>= 1) v = fminf(v, __shfl_down(v, o, 64));
    return v;
}
__device__ __forceinline__ float wmax64(float v) {
#pragma unroll
    for (int o = 32; o > 0; o >>= 1) v = fmaxf(v, __shfl_down(v, o, 64));
    return v;
}

// K1: 512 blocks x 256 thr. Cold coalesced read of the block's 256x32 feat
// tile; norm accumulate while stashing in padded LDS; v-partials from LDS.
// Plain stores (visible to K2 via kernel boundary). Zeroes K2's counters.
__global__ void __launch_bounds__(256) k_norm_vpart(
    const float* __restrict__ cam, const float* __restrict__ feat,
    float* __restrict__ s, float* __restrict__ v_part,
    unsigned int* __restrict__ cnt)
{
    if (blockIdx.x == 0 && threadIdx.x < 3)
        __hip_atomic_store(&cnt[threadIdx.x], 0u, __ATOMIC_RELAXED, SCOPE_AGENT);

    __shared__ float tile[C * 33];   // [c][pix], stride 33: 2-way alias = free
    __shared__ float red[8][33];
    __shared__ float w_sh[32];

    const int t   = threadIdx.x;
    const int pix = t & 31;
    const int g   = t >> 5;          // channel group 0..7
    const int bk  = blockIdx.x;
    const int b   = bk >> 7;         // 128 blocks per batch
    const int n0  = (bk * 32) & (N - 1);

    {
        const float* fp = feat + (size_t)b * CN + (size_t)(g * 32) * N + n0 + pix;
        float ss = 0.f;
#pragma unroll
        for (int cc = 0; cc < 32; ++cc) {
            float x = fp[(size_t)cc * N];            // 32-lane contiguous, 128B lines
            ss = fmaf(x, x, ss);
            tile[(g * 32 + cc) * 33 + pix] = x;
        }
        red[g][pix] = ss;
    }
    __syncthreads();
    if (t < 32) {
        float tot = 0.f;
#pragma unroll
        for (int gg = 0; gg < 8; ++gg) tot += red[gg][t];
        float cv = cam[bk * 32 + t];
        float m  = ((cv >= 0.3f ? 1.f : 0.f) + (cv >= 0.4f ? 1.f : 0.f) +
                    (cv >= 0.5f ? 1.f : 0.f)) * (1.f / 3.f);
        float sc = m / fmaxf(m * sqrtf(tot), 1e-12f);  // ||feat*m|| = m*||feat||
        s[bk * 32 + t] = sc;
        w_sh[t] = sc * cv;
    }
    __syncthreads();
    {
        float acc = 0.f;
#pragma unroll
        for (int pp = 0; pp < 32; ++pp)
            acc = fmaf(tile[t * 33 + pp], w_sh[pp], acc);
        v_part[bk * 256 + t] = acc;                  // coalesced plain store
    }
}

// K2: 512 blocks x 256 thr. Blocks 0..15 reduce v first; all blocks stash
// their (L3-hot) feat tile; spin for v; dot; global minmax barrier; rescale
// own 32 pixels from registers; loss via last-block fixed-order sum.
__global__ void __launch_bounds__(256) k_main(
    const float* __restrict__ feat, const float* __restrict__ s,
    const float* __restrict__ cam, const float* __restrict__ v_part,
    float* __restrict__ v, float* __restrict__ bmn, float* __restrict__ bmx,
    float* __restrict__ part, float* __restrict__ out,
    unsigned int* __restrict__ cnt)
{
    __shared__ float tile[C * 33];
    __shared__ float red[8][33];
    __shared__ float vred[4][64];
    __shared__ float vs[C];
    __shared__ float sh[2];
    __shared__ int lastflag;

    const int t   = threadIdx.x;
    const int pix = t & 31;
    const int g   = t >> 5;
    const int bk  = blockIdx.x;
    const int b   = bk >> 7;
    const int n0  = (bk * 32) & (N - 1);

    // ---- v-reduce (blocks 0..15), before own tile load so others unblock fast
    if (bk < NRED) {
        const int l  = t & 63;
        const int ks = t >> 6;                      // 4-way split-k
        const int bc = bk * 64 + l;                 // output index 0..1023
        const int vb = bc >> 8, c = bc & 255;
        const float* vp = v_part + (size_t)vb * (128 * 256) + c;
        float a = 0.f;
#pragma unroll
        for (int kk = 0; kk < 32; ++kk)
            a += vp[(size_t)(ks * 32 + kk) * 256];
        vred[ks][l] = a;
        __syncthreads();                            // block-uniform path
        if (t < 64) {
            float tot = (vred[0][t] + vred[1][t]) + (vred[2][t] + vred[3][t]);
            __hip_atomic_store(&v[bk * 64 + t], tot, __ATOMIC_RELAXED, SCOPE_AGENT);
        }
        if (t == 0)
            __hip_atomic_fetch_add(&cnt[0], 1u, __ATOMIC_ACQ_REL, SCOPE_AGENT);
    }

    // ---- stash this block's feat tile (Infinity-Cache-hot) into LDS
    {
        const float* fp = feat + (size_t)b * CN + (size_t)(g * 32) * N + n0 + pix;
#pragma unroll
        for (int cc = 0; cc < 32; ++cc)
            tile[(g * 32 + cc) * 33 + pix] = fp[(size_t)cc * N];
    }

    // ---- wait for v, load it
    if (t == 0)
        while (__hip_atomic_load(&cnt[0], __ATOMIC_ACQUIRE, SCOPE_AGENT) < NRED)
            __builtin_amdgcn_s_sleep(1);
    __syncthreads();
    vs[t] = __hip_atomic_load(&v[b * 256 + t], __ATOMIC_RELAXED, SCOPE_AGENT);
    __syncthreads();

    // ---- o = s * (feat[:,n] . v) from LDS
    float acc = 0.f;
#pragma unroll 8
    for (int cc = 0; cc < 32; ++cc)
        acc = fmaf(tile[(g * 32 + cc) * 33 + pix], vs[g * 32 + cc], acc);
    red[g][pix] = acc;
    __syncthreads();

    float o = 0.f;
    if (t < 32) {
        float tot = 0.f;
#pragma unroll
        for (int gg = 0; gg < 8; ++gg) tot += red[gg][t];
        o = s[bk * 32 + t] * tot;
        float mn = o, mx = o;
#pragma unroll
        for (int o2 = 16; o2 > 0; o2 >>= 1) {
            mn = fminf(mn, __shfl_down(mn, o2, 64));
            mx = fmaxf(mx, __shfl_down(mx, o2, 64));
        }
        if (t == 0) {
            __hip_atomic_store(&bmn[bk], mn, __ATOMIC_RELAXED, SCOPE_AGENT);
            __hip_atomic_store(&bmx[bk], mx, __ATOMIC_RELAXED, SCOPE_AGENT);
        }
    }

    // ---- global barrier on block min/max (atomics only, no fence)
    if (t == 0) {
        __hip_atomic_fetch_add(&cnt[1], 1u, __ATOMIC_ACQ_REL, SCOPE_AGENT);
        while (__hip_atomic_load(&cnt[1], __ATOMIC_ACQUIRE, SCOPE_AGENT) < (unsigned)NBLK)
            __builtin_amdgcn_s_sleep(1);
    }
    __syncthreads();

    // ---- batch min/max (own batch, 128 entries)
    if (t < 64) {
        float a = fminf(
            __hip_atomic_load(&bmn[b * 128 + t],      __ATOMIC_RELAXED, SCOPE_AGENT),
            __hip_atomic_load(&bmn[b * 128 + 64 + t], __ATOMIC_RELAXED, SCOPE_AGENT));
        a = wmin64(a);
        if (t == 0) sh[0] = a;
    } else if (t < 128) {
        int l = t - 64;
        float z = fmaxf(
            __hip_atomic_load(&bmx[b * 128 + l],      __ATOMIC_RELAXED, SCOPE_AGENT),
            __hip_atomic_load(&bmx[b * 128 + 64 + l], __ATOMIC_RELAXED, SCOPE_AGENT));
        z = wmax64(z);
        if (l == 0) sh[1] = z;
    }
    __syncthreads();

    // ---- rescale own 32 pixels (held in wave-0 registers), loss partial
    if (t < 32) {
        float mn  = sh[0];
        float mxa = sh[1] + 1e-5f;
        float r = (o - mn) / (mxa - mn);
        out[bk * 32 + t] = r;
        float ad = fabsf(r - cam[bk * 32 + t]);
#pragma unroll
        for (int o2 = 16; o2 > 0; o2 >>= 1) ad += __shfl_down(ad, o2, 64);
        if (t == 0)
            __hip_atomic_store(&part[bk], ad, __ATOMIC_RELAXED, SCOPE_AGENT);
    }
    if (t == 0) {
        unsigned old = __hip_atomic_fetch_add(&cnt[2], 1u, __ATOMIC_ACQ_REL, SCOPE_AGENT);
        lastflag = (old == (unsigned)(NBLK - 1)) ? 1 : 0;
    }
    __syncthreads();
    if (!lastflag) return;

    // ---- last block: fixed-order loss sum (deterministic)
    if (t < 64) {
        float x = 0.f;
#pragma unroll
        for (int j = 0; j < 8; ++j)
            x += __hip_atomic_load(&part[t + 64 * j], __ATOMIC_RELAXED, SCOPE_AGENT);
        x = wsum(x);
        if (t == 0) out[BN] = x * (1.f / (float)BN);
    }
}

extern "C" void kernel_launch(void* const* d_in, const int* in_sizes, int n_in,
                              void* d_out, int out_size, void* d_ws, size_t ws_size,
                              hipStream_t stream) {
    const float* cam  = (const float*)d_in[0];   // (4,64,64)
    const float* feat = (const float*)d_in[1];   // (4,256,64,64)
    float* out = (float*)d_out;                  // [16384 ref][1 loss]
    float* ws  = (float*)d_ws;

    float* s      = ws;                   // 16384
    float* v_part = ws + 16384;           // 512*256 = 131072
    float* v      = ws + 147456;          // 1024
    float* bmn    = ws + 148480;          // 512
    float* bmx    = ws + 148992;          // 512
    float* part   = ws + 149504;          // 512
    unsigned int* cnt = (unsigned int*)(ws + 150016);   // 3

    k_norm_vpart<<<NBLK, 256, 0, stream>>>(cam, feat, s, v_part, cnt);
    k_main      <<<NBLK, 256, 0, stream>>>(feat, s, cam, v_part, v, bmn, bmx,
                                           part, out, cnt);
}

// Round 7
// 18.896 us; speedup vs baseline: 3.4555x; 3.4555x over previous
//
#include <hip/hip_runtime.h>

// RefinementCAM: B=4, C=256, H=W=64, N=4096.
// out[b,n] = s[b,n] * (feat[b,:,n] . v[b,:]),
//   v[b,c] = sum_m feat[b,c,m] * w[b,m],  w = s*cam,
//   s = m/max(m*||feat[:,n]||,1e-12),  m in {0,1/3,2/3,1}.
// R3 skeleton (4 kernels, no intra-kernel global barriers, no fences) with
// k_v's full feat pass replaced by K1 LDS-stash v-partials + tiny reduce.

constexpr int B    = 4;
constexpr int C    = 256;
constexpr int N    = 4096;
constexpr int BN   = B * N;       // 16384
constexpr int CN   = C * N;
constexpr int NBLK = 512;         // K1/K3 blocks (32 pixels each)

#define SCOPE_AGENT __HIP_MEMORY_SCOPE_AGENT

__device__ __forceinline__ float wsum(float v) {
#pragma unroll
    for (int o = 32; o > 0; o >>= 1) v += __shfl_down(v, o, 64);
    return v;
}
__device__ __forceinline__ float wmin64(float v) {
#pragma unroll
    for (int o = 32; o > 0; o >>= 1) v = fminf(v, __shfl_down(v, o, 64));
    return v;
}
__device__ __forceinline__ float wmax64(float v) {
#pragma unroll
    for (int o = 32; o > 0; o >>= 1) v = fmaxf(v, __shfl_down(v, o, 64));
    return v;
}

// K1: 512 blocks x 256 thr. Cold coalesced read of the block's 256x32 feat
// tile; norm accumulate while stashing in padded LDS; v-partials from LDS.
// Plain stores only (kernel boundary = visibility). Zeroes k_final's counter.
__global__ void __launch_bounds__(256) k_norm_vpart(
    const float* __restrict__ cam, const float* __restrict__ feat,
    float* __restrict__ s, float* __restrict__ v_part,
    unsigned int* __restrict__ cnt)
{
    if (blockIdx.x == 0 && threadIdx.x == 0) *cnt = 0u;

    __shared__ float tile[C * 33];   // [c][pix], stride 33: 2-way alias = free
    __shared__ float red[8][33];
    __shared__ float w_sh[32];

    const int t   = threadIdx.x;
    const int pix = t & 31;
    const int g   = t >> 5;          // channel group 0..7
    const int bk  = blockIdx.x;
    const int b   = bk >> 7;         // 128 blocks per batch
    const int n0  = (bk * 32) & (N - 1);

    {
        const float* fp = feat + (size_t)b * CN + (size_t)(g * 32) * N + n0 + pix;
        float ss = 0.f;
#pragma unroll
        for (int cc = 0; cc < 32; ++cc) {
            float x = fp[(size_t)cc * N];            // 32-lane contiguous
            ss = fmaf(x, x, ss);
            tile[(g * 32 + cc) * 33 + pix] = x;
        }
        red[g][pix] = ss;
    }
    __syncthreads();
    if (t < 32) {
        float tot = 0.f;
#pragma unroll
        for (int gg = 0; gg < 8; ++gg) tot += red[gg][t];
        float cv = cam[bk * 32 + t];
        float m  = ((cv >= 0.3f ? 1.f : 0.f) + (cv >= 0.4f ? 1.f : 0.f) +
                    (cv >= 0.5f ? 1.f : 0.f)) * (1.f / 3.f);
        float sc = m / fmaxf(m * sqrtf(tot), 1e-12f);  // ||feat*m|| = m*||feat||
        s[bk * 32 + t] = sc;
        w_sh[t] = sc * cv;
    }
    __syncthreads();
    {
        float acc = 0.f;
#pragma unroll
        for (int pp = 0; pp < 32; ++pp)
            acc = fmaf(tile[t * 33 + pp], w_sh[pp], acc);   // stride-33: conflict-free
        v_part[bk * 256 + t] = acc;                  // coalesced plain store
    }
}

// K2: 16 blocks x 256 thr. v[bc] = sum of 128 block-partials (4-way split-k).
__global__ void __launch_bounds__(256) k_vreduce(
    const float* __restrict__ v_part, float* __restrict__ v)
{
    __shared__ float vred[4][64];
    const int t  = threadIdx.x;
    const int l  = t & 63;
    const int ks = t >> 6;                       // split-k 0..3
    const int bc = blockIdx.x * 64 + l;          // 0..1023
    const int vb = bc >> 8, c = bc & 255;
    const float* vp = v_part + (size_t)vb * (128 * 256) + c;
    float a = 0.f;
#pragma unroll
    for (int kk = 0; kk < 32; ++kk)
        a += vp[(size_t)(ks * 32 + kk) * 256];   // coalesced across lanes
    vred[ks][l] = a;
    __syncthreads();
    if (t < 64)
        v[bc] = (vred[0][t] + vred[1][t]) + (vred[2][t] + vred[3][t]);
}

// K3: 512 blocks x 256 thr (R3 verbatim). ob = s*(feat[:,n].v); block min/max.
__global__ void __launch_bounds__(256) k_out(
    const float* __restrict__ feat, const float* __restrict__ s,
    const float* __restrict__ v, float* __restrict__ ob,
    float* __restrict__ bmn, float* __restrict__ bmx)
{
    const int t   = threadIdx.x;
    const int pix = t & 31;
    const int g   = t >> 5;
    const int bk  = blockIdx.x;
    const int b   = bk >> 7;
    const int n0  = (bk * 32) & (N - 1);

    __shared__ float vs[C];
    vs[t] = v[b * C + t];
    __syncthreads();

    const float* fp = feat + (size_t)b * CN + (size_t)(g * 32) * N + n0 + pix;
    float acc = 0.f;
#pragma unroll 8
    for (int cc = 0; cc < 32; ++cc)
        acc = fmaf(fp[(size_t)cc * N], vs[g * 32 + cc], acc);  // vs broadcast

    __shared__ float red[8][33];
    red[g][pix] = acc;
    __syncthreads();
    if (t < 32) {
        float tot = 0.f;
#pragma unroll
        for (int gg = 0; gg < 8; ++gg) tot += red[gg][t];
        float o = s[bk * 32 + t] * tot;
        ob[bk * 32 + t] = o;
        float mn = o, mx = o;
#pragma unroll
        for (int o2 = 16; o2 > 0; o2 >>= 1) {
            mn = fminf(mn, __shfl_down(mn, o2, 64));
            mx = fmaxf(mx, __shfl_down(mx, o2, 64));
        }
        if (t == 0) { bmn[bk] = mn; bmx[bk] = mx; }
    }
}

// K4: 64 blocks x 256 thr (R3 verbatim). Batch minmax, rescale, |ref-cam|;
// last block finishes the loss with a fixed-order (deterministic) sum.
__global__ void __launch_bounds__(256) k_final(
    const float* __restrict__ ob, const float* __restrict__ cam,
    const float* __restrict__ bmn, const float* __restrict__ bmx,
    float* __restrict__ out, float* __restrict__ part, unsigned int* __restrict__ cnt)
{
    const int t = threadIdx.x, blk = blockIdx.x;
    const int p = blk * 256 + t;
    const int b = blk >> 4;                 // 16 blocks per batch

    __shared__ float sh[2];
    if (t < 64) {
        float a = fminf(bmn[b * 128 + t], bmn[b * 128 + 64 + t]);
        a = wmin64(a);
        if (t == 0) sh[0] = a;
    } else if (t < 128) {
        int l = t - 64;
        float a = fmaxf(bmx[b * 128 + l], bmx[b * 128 + 64 + l]);
        a = wmax64(a);
        if (l == 0) sh[1] = a;
    }
    __syncthreads();
    const float mn = sh[0];
    const float mx = sh[1] + 1e-5f;

    float r = (ob[p] - mn) / (mx - mn);
    out[p] = r;
    float ad = fabsf(r - cam[p]);

    __shared__ float red[4];
    float ps = wsum(ad);
    if ((t & 63) == 0) red[t >> 6] = ps;
    __syncthreads();

    __shared__ int lastflag;
    if (t == 0) {
        float tot = (red[0] + red[1]) + (red[2] + red[3]);
        __hip_atomic_store(&part[blk], tot, __ATOMIC_RELEASE, SCOPE_AGENT);
        unsigned old = __hip_atomic_fetch_add(cnt, 1u, __ATOMIC_ACQ_REL, SCOPE_AGENT);
        lastflag = (old == 63u) ? 1 : 0;
    }
    __syncthreads();
    if (lastflag && t < 64) {
        float x = __hip_atomic_load(&part[t], __ATOMIC_ACQUIRE, SCOPE_AGENT);
        x = wsum(x);                        // fixed-order: deterministic
        if (t == 0) out[BN] = x * (1.f / (float)BN);
    }
}

extern "C" void kernel_launch(void* const* d_in, const int* in_sizes, int n_in,
                              void* d_out, int out_size, void* d_ws, size_t ws_size,
                              hipStream_t stream) {
    const float* cam  = (const float*)d_in[0];   // (4,64,64)
    const float* feat = (const float*)d_in[1];   // (4,256,64,64)
    float* out = (float*)d_out;                  // [16384 ref][1 loss]
    float* ws  = (float*)d_ws;

    float* s      = ws;                   // 16384
    float* v_part = ws + 16384;           // 512*256 = 131072
    float* v      = ws + 147456;          // 1024
    float* ob     = ws + 148480;          // 16384
    float* bmn    = ws + 164864;          // 512
    float* bmx    = ws + 165376;          // 512
    float* part   = ws + 165888;          // 64
    unsigned int* cnt = (unsigned int*)(ws + 165952);

    k_norm_vpart<<<NBLK, 256, 0, stream>>>(cam, feat, s, v_part, cnt);
    k_vreduce   <<<16,   256, 0, stream>>>(v_part, v);
    k_out       <<<NBLK, 256, 0, stream>>>(feat, s, v, ob, bmn, bmx);
    k_final     <<<64,   256, 0, stream>>>(ob, cam, bmn, bmx, out, part, cnt);
}